// Round 7
// baseline (521.957 us; speedup 1.0000x reference)
//
#include <hip/hip_runtime.h>
#include <hip/hip_bf16.h>

#define NB 2
#define NC 256
#define NN 4096
#define NG 16
#define GSZ (16*NN)      // elements per (b,group) = 65536, contiguous in x
#define SPLIT 4
#define JT (NN / SPLIT / 64)   // j-tiles per split = 16
#define SCL 0.09014205f  // log2(e) / sqrt(256)
#define THRRAW 88.0f     // defer-max threshold in raw score units (~8/SCL)

typedef __attribute__((ext_vector_type(8))) short bf16x8;
typedef __attribute__((ext_vector_type(4))) float f32x4;
typedef __attribute__((ext_vector_type(8))) unsigned short u16x8;

static __device__ __forceinline__ unsigned short f2b(float f) {
    union { float f; unsigned u; } x; x.f = f;
    unsigned r = x.u + 0x7fffu + ((x.u >> 16) & 1u);
    return (unsigned short)(r >> 16);
}
static __device__ __forceinline__ float b2f(unsigned short u) {
    union { unsigned u; float f; } x; x.u = ((unsigned)u) << 16;
    return x.f;
}
// async global->LDS, 16B per lane; LDS dest must be wave-uniform base (+lane*16)
static __device__ __forceinline__ void glds16(const void* g, void* l) {
    __builtin_amdgcn_global_load_lds(
        (const __attribute__((address_space(1))) unsigned int*)g,
        (__attribute__((address_space(3))) unsigned int*)l, 16, 0, 0);
}

// ---------------- weights f32 -> bf16 (wq|wk|wv|wp) ----------------
__global__ void k_wcvt(const float* __restrict__ wq, const float* __restrict__ wk,
                       const float* __restrict__ wv, const float* __restrict__ wp,
                       unsigned short* __restrict__ dst) {
    int idx = (blockIdx.x * 256 + threadIdx.x) * 4;   // 0..262140
    int which = idx >> 16, off = idx & 65535;
    const float* s = (which == 0) ? wq : (which == 1) ? wk : (which == 2) ? wv : wp;
    float4 v = *(const float4*)(s + off);
    dst[idx + 0] = f2b(v.x);
    dst[idx + 1] = f2b(v.y);
    dst[idx + 2] = f2b(v.z);
    dst[idx + 3] = f2b(v.w);
}

// ---------------- group-norm sums: 8 blocks per (b,g), atomic accumulate ----------------
__global__ void k_stats(const float* __restrict__ x, float* __restrict__ stats) {
    int bg = blockIdx.x >> 3, seg = blockIdx.x & 7;   // 32 groups x 8 segments
    const float4* p = (const float4*)(x + (size_t)bg * GSZ + (size_t)seg * (GSZ / 8));
    float s1 = 0.f, s2 = 0.f;
    for (int k = threadIdx.x; k < GSZ / 8 / 4; k += 256) {
        float4 v = p[k];
        s1 += v.x + v.y + v.z + v.w;
        s2 += v.x*v.x + v.y*v.y + v.z*v.z + v.w*v.w;
    }
    #pragma unroll
    for (int m = 1; m < 64; m <<= 1) { s1 += __shfl_xor(s1, m); s2 += __shfl_xor(s2, m); }
    __shared__ float r1[4], r2[4];
    int w = threadIdx.x >> 6;
    if ((threadIdx.x & 63) == 0) { r1[w] = s1; r2[w] = s2; }
    __syncthreads();
    if (threadIdx.x == 0) {
        float a = 0.f, b = 0.f;
        #pragma unroll
        for (int i = 0; i < 4; i++) { a += r1[i]; b += r2[i]; }
        atomicAdd(&stats[bg * 2], a);
        atomicAdd(&stats[bg * 2 + 1], b);
    }
}

// ---------------- normalize + transpose -> hn_t[b][n][c] bf16 ----------------
__global__ void k_norm_t(const float* __restrict__ x, const float* __restrict__ gamma,
                         const float* __restrict__ beta, const float* __restrict__ stats,
                         unsigned short* __restrict__ hn_t) {
    __shared__ unsigned short tile[64][66];
    int n0 = blockIdx.x * 64, c0 = blockIdx.y * 64, b = blockIdx.z;
    int cc = threadIdx.x >> 2, part = threadIdx.x & 3;
    int c = c0 + cc;
    float s1 = stats[(b * NG + (c >> 4)) * 2];
    float s2 = stats[(b * NG + (c >> 4)) * 2 + 1];
    float mean = s1 * (1.f / (float)GSZ);
    float var  = s2 * (1.f / (float)GSZ) - mean * mean;
    float rstd = rsqrtf(var + 1e-6f);
    float sc = rstd * gamma[c];
    float sh = beta[c] - mean * sc;
    const float4* row = (const float4*)(x + ((size_t)b * NC + c) * NN + n0);
    #pragma unroll
    for (int q = 0; q < 4; q++) {
        int f4 = part * 4 + q;
        float4 v = row[f4];
        tile[cc][f4*4+0] = f2b(v.x * sc + sh);
        tile[cc][f4*4+1] = f2b(v.y * sc + sh);
        tile[cc][f4*4+2] = f2b(v.z * sc + sh);
        tile[cc][f4*4+3] = f2b(v.w * sc + sh);
    }
    __syncthreads();
    int nn = threadIdx.x >> 2;
    u16x8 o0, o1;
    #pragma unroll
    for (int e = 0; e < 8; e++) { o0[e] = tile[part*16 + e][nn]; o1[e] = tile[part*16 + 8 + e][nn]; }
    unsigned short* dst = hn_t + ((size_t)b * NN + n0 + nn) * NC + c0 + part * 16;
    *(u16x8*)dst = o0;
    *(u16x8*)(dst + 8) = o1;
}

// ---------------- QKV GEMM ----------------
// q,k: C[i][o] -> q_t/k_t[b][i][c].  v: operand-swapped C[o][i] -> v_cm[b][c][n].
__global__ __launch_bounds__(256, 2) void k_qkv(
        const unsigned short* __restrict__ hn_t, const unsigned short* __restrict__ wb,
        const float* __restrict__ bq, const float* __restrict__ bk, const float* __restrict__ bv,
        unsigned short* __restrict__ q_t, unsigned short* __restrict__ k_t,
        unsigned short* __restrict__ v_cm) {
    int i0 = blockIdx.x * 64, which = blockIdx.y, b = blockIdx.z;
    int lane = threadIdx.x & 63, w = threadIdx.x >> 6;
    const unsigned short* W = wb + which * 65536;
    const float* bias = (which == 0) ? bq : (which == 1) ? bk : bv;
    if (which < 2) {
        const unsigned short* arow =
            hn_t + ((size_t)b * NN + i0 + w * 16 + (lane & 15)) * NC + ((lane >> 4) * 8);
        f32x4 acc[16];
        #pragma unroll
        for (int t = 0; t < 16; t++) acc[t] = (f32x4){0.f, 0.f, 0.f, 0.f};
        #pragma unroll
        for (int kk = 0; kk < 8; kk++) {
            bf16x8 af = *(const bf16x8*)(arow + kk * 32);
            const unsigned short* bbase = W + (size_t)(lane & 15) * NC + kk * 32 + ((lane >> 4) * 8);
            #pragma unroll
            for (int ot = 0; ot < 16; ot++) {
                bf16x8 bf_ = *(const bf16x8*)(bbase + (size_t)ot * 16 * NC);
                acc[ot] = __builtin_amdgcn_mfma_f32_16x16x32_bf16(af, bf_, acc[ot], 0, 0, 0);
            }
        }
        unsigned short* dst = ((which == 0) ? q_t : k_t) + (size_t)b * NN * NC;
        #pragma unroll
        for (int ot = 0; ot < 16; ot++) {
            float bv_ = bias[ot * 16 + (lane & 15)];
            #pragma unroll
            for (int r = 0; r < 4; r++) {
                int i = i0 + w * 16 + (lane >> 4) * 4 + r;
                dst[(size_t)i * NC + ot * 16 + (lane & 15)] = f2b(acc[ot][r] + bv_);
            }
        }
    } else {
        // wave w owns o-range [w*64, +64); C[o][i] = sum_c wv[o][c] hn[i][c]
        f32x4 acc[4][4];
        #pragma unroll
        for (int mt = 0; mt < 4; mt++)
            #pragma unroll
            for (int nt = 0; nt < 4; nt++) acc[mt][nt] = (f32x4){0.f, 0.f, 0.f, 0.f};
        #pragma unroll
        for (int kk = 0; kk < 8; kk++) {
            bf16x8 bfr[4];
            #pragma unroll
            for (int nt = 0; nt < 4; nt++)
                bfr[nt] = *(const bf16x8*)(hn_t + ((size_t)b * NN + i0 + nt * 16 + (lane & 15)) * NC
                                           + kk * 32 + ((lane >> 4) * 8));
            #pragma unroll
            for (int mt = 0; mt < 4; mt++) {
                bf16x8 af = *(const bf16x8*)(W + (size_t)(w * 64 + mt * 16 + (lane & 15)) * NC
                                             + kk * 32 + ((lane >> 4) * 8));
                #pragma unroll
                for (int nt = 0; nt < 4; nt++)
                    acc[mt][nt] = __builtin_amdgcn_mfma_f32_16x16x32_bf16(af, bfr[nt], acc[mt][nt], 0, 0, 0);
            }
        }
        #pragma unroll
        for (int mt = 0; mt < 4; mt++) {
            #pragma unroll
            for (int r = 0; r < 4; r++) {
                int o = w * 64 + mt * 16 + (lane >> 4) * 4 + r;
                float bv_ = bias[o];
                #pragma unroll
                for (int nt = 0; nt < 4; nt++) {
                    int i = i0 + nt * 16 + (lane & 15);
                    v_cm[(size_t)b * NC * NN + (size_t)o * NN + i] = f2b(acc[mt][nt][r] + bv_);
                }
            }
        }
    }
}

// ---------------- flash attention: 8 waves x 16 i-rows, K staged (dbuf glds), ----------
// ---------------- V direct from L2, P wave-local, defer-max, 1 barrier/tile ----------
// grid 256: bid&7 -> (sp,b) (XCD-grouped), bid>>3 -> i-block (128 rows).
__global__ __launch_bounds__(512, 4) void k_attn(
        const unsigned short* __restrict__ q_t, const unsigned short* __restrict__ k_t,
        const unsigned short* __restrict__ v_cm,
        unsigned short* __restrict__ po, float* __restrict__ ml) {
    __shared__ __attribute__((aligned(16))) unsigned short Ks[2][16384]; // [j 64][c 256] swz
    __shared__ __attribute__((aligned(16))) unsigned short Ps[8][1024];  // [i 16][j 64] swz
    int bid = blockIdx.x;
    int g = bid & 7, xb = bid >> 3;
    int sp = g & 3, b = g >> 2;
    int i0 = xb * 128;
    int lane = threadIdx.x & 63, w = threadIdx.x >> 6;
    size_t bO = (size_t)b * NN * NC;
    // Q fragments (wave w owns rows i0+w*16 .. +16)
    bf16x8 qf[8];
    {
        const unsigned short* qrow =
            q_t + bO + (size_t)(i0 + w * 16 + (lane & 15)) * NC + ((lane >> 4) * 8);
        #pragma unroll
        for (int kk = 0; kk < 8; kk++) qf[kk] = *(const bf16x8*)(qrow + kk * 32);
    }
    // K staging: per-lane pre-swizzled global offsets (linear LDS dest)
    unsigned kstat[4];
    #pragma unroll
    for (int r = 0; r < 4; r++) {
        int jr = r * 16 + w * 2 + (lane >> 5);
        kstat[r] = (unsigned)(jr * 512 + (((lane & 31) * 16) ^ ((jr & 7) << 4)));
    }
    const char* kp = (const char*)(k_t + bO) + (size_t)sp * 524288;  // sp*1024 rows * 512B
    // V direct-read per-lane base: row (lane&15), j-sub (lane>>4)*8
    const unsigned short* vbase = v_cm + bO + (size_t)(lane & 15) * NN + ((lane >> 4) * 8)
                                  + (size_t)sp * 1024;
    f32x4 o[16];
    #pragma unroll
    for (int t = 0; t < 16; t++) o[t] = (f32x4){0.f, 0.f, 0.f, 0.f};
    float m[4], l[4];
    #pragma unroll
    for (int r = 0; r < 4; r++) { m[r] = -1e30f; l[r] = 0.f; }
    // prologue: stage K tile 0 into buf 0
    #pragma unroll
    for (int r = 0; r < 4; r++)
        glds16(kp + kstat[r], (char*)&Ks[0][0] + w * 1024 + r * 8192);
    __syncthreads();
    int cur = 0;
    #pragma unroll 1
    for (int t = 0; t < JT; ++t) {
        if (t < JT - 1) {   // prefetch next K tile into alt buffer (overlaps compute)
            kp += 32768;
            int nb = cur ^ 1;
            #pragma unroll
            for (int r = 0; r < 4; r++)
                glds16(kp + kstat[r], (char*)&Ks[nb][0] + w * 1024 + r * 8192);
        }
        const char* KsB = (const char*)&Ks[cur][0];
        // S = Q K^T
        f32x4 s[4];
        #pragma unroll
        for (int tt = 0; tt < 4; tt++) s[tt] = (f32x4){0.f, 0.f, 0.f, 0.f};
        __builtin_amdgcn_s_setprio(1);
        #pragma unroll
        for (int kk = 0; kk < 8; kk++) {
            #pragma unroll
            for (int tt = 0; tt < 4; tt++) {
                unsigned off = ((unsigned)((tt * 16 + (lane & 15)) * 512 + kk * 64 + ((lane >> 4) * 16)))
                               ^ (((unsigned)(lane & 7)) << 4);
                bf16x8 kf = *(const bf16x8*)(KsB + off);
                s[tt] = __builtin_amdgcn_mfma_f32_16x16x32_bf16(qf[kk], kf, s[tt], 0, 0, 0);
            }
        }
        __builtin_amdgcn_s_setprio(0);
        // online softmax with deferred rescale (T13)
        float vmax[4];
        #pragma unroll
        for (int r = 0; r < 4; r++) {
            float v0 = fmaxf(fmaxf(s[0][r], s[1][r]), fmaxf(s[2][r], s[3][r]));
            v0 = fmaxf(v0, __shfl_xor(v0, 1));
            v0 = fmaxf(v0, __shfl_xor(v0, 2));
            v0 = fmaxf(v0, __shfl_xor(v0, 4));
            v0 = fmaxf(v0, __shfl_xor(v0, 8));
            vmax[r] = v0;
        }
        float tmax = fmaxf(fmaxf(vmax[0] - m[0], vmax[1] - m[1]),
                           fmaxf(vmax[2] - m[2], vmax[3] - m[3]));
        tmax = fmaxf(tmax, __shfl_xor(tmax, 16));
        tmax = fmaxf(tmax, __shfl_xor(tmax, 32));
        if (tmax > THRRAW) {    // wave-uniform rescale
            #pragma unroll
            for (int r = 0; r < 4; r++) {
                float mn = fmaxf(m[r], vmax[r]);
                float corr = exp2f((m[r] - mn) * SCL);
                m[r] = mn;
                l[r] *= corr;
                #pragma unroll
                for (int ct = 0; ct < 16; ct++) o[ct][r] *= corr;
            }
        }
        float rs[4] = {0.f, 0.f, 0.f, 0.f};
        #pragma unroll
        for (int tt = 0; tt < 4; tt++) {
            #pragma unroll
            for (int r = 0; r < 4; r++) {
                float p = exp2f((s[tt][r] - m[r]) * SCL);
                rs[r] += p;
                unsigned i_ = (unsigned)((lane >> 4) * 4 + r);
                unsigned off = ((unsigned)(i_ * 128 + (tt * 16 + (lane & 15)) * 2)) ^ ((i_ & 7) << 4);
                *(unsigned short*)((char*)&Ps[w][0] + off) = f2b(p);
            }
        }
        #pragma unroll
        for (int r = 0; r < 4; r++) {
            float v0 = rs[r];
            v0 += __shfl_xor(v0, 1); v0 += __shfl_xor(v0, 2);
            v0 += __shfl_xor(v0, 4); v0 += __shfl_xor(v0, 8);
            l[r] += v0;
        }
        // O += P V : A = P (wave-local LDS), B = V from global (L2-resident slice)
        const unsigned short* vt = vbase + (size_t)t * 64;
        __builtin_amdgcn_s_setprio(1);
        #pragma unroll
        for (int kj = 0; kj < 2; kj++) {
            unsigned offp = ((unsigned)((lane & 15) * 128 + kj * 64 + ((lane >> 4) * 16)))
                            ^ (((unsigned)(lane & 7)) << 4);
            bf16x8 pf = *(const bf16x8*)((char*)&Ps[w][0] + offp);
            #pragma unroll
            for (int ct = 0; ct < 16; ct++) {
                bf16x8 vf = *(const bf16x8*)(vt + (size_t)ct * 16 * NN + kj * 32);
                o[ct] = __builtin_amdgcn_mfma_f32_16x16x32_bf16(pf, vf, o[ct], 0, 0, 0);
            }
        }
        __builtin_amdgcn_s_setprio(0);
        __syncthreads();   // drains K glds (vmcnt) + protects K buffer + P reuse
        cur ^= 1;
    }
    // write unnormalized partial O and (m, l)
    unsigned short* dst = po + (size_t)(sp * NB + b) * NN * NC;
    #pragma unroll
    for (int ct = 0; ct < 16; ct++) {
        #pragma unroll
        for (int r = 0; r < 4; r++) {
            int i = i0 + w * 16 + (lane >> 4) * 4 + r;
            dst[(size_t)i * NC + ct * 16 + (lane & 15)] = f2b(o[ct][r]);
        }
    }
    if ((lane & 15) == 0) {
        #pragma unroll
        for (int r = 0; r < 4; r++) {
            int i = i0 + w * 16 + (lane >> 4) * 4 + r;
            size_t mi = ((size_t)(sp * NB + b) * NN + i) * 2;
            ml[mi] = m[r];
            ml[mi + 1] = l[r];
        }
    }
}

// ---------------- fused combine + projection + residual ----------------
// block: i-tile 32, all 256 o. C[o][i] = sum_c wp[o][c] ho[i][c]; out = x + C + bp.
__global__ __launch_bounds__(256, 4) void k_proj(
        const unsigned short* __restrict__ po, const float* __restrict__ ml,
        const unsigned short* __restrict__ wp_b, const float* __restrict__ bp,
        const float* __restrict__ x, float* __restrict__ out) {
    __shared__ __attribute__((aligned(16))) unsigned short Hs[32 * 256]; // [i 32][c 256] swz
    int i0 = blockIdx.x * 32, b = blockIdx.y;
    int tid = threadIdx.x, lane = tid & 63, w = tid >> 6;
    {   // combine SPLIT splits -> Hs (combine weights computed inline)
        int il = tid >> 3, cq = tid & 7;
        int i = i0 + il;
        float mv[SPLIT], lv[SPLIT];
        float M = -1e30f;
        #pragma unroll
        for (int s = 0; s < SPLIT; s++) {
            size_t mi = ((size_t)(s * NB + b) * NN + i) * 2;
            mv[s] = ml[mi]; lv[s] = ml[mi + 1];
            M = fmaxf(M, mv[s]);
        }
        float den = 0.f, wg[SPLIT];
        #pragma unroll
        for (int s = 0; s < SPLIT; s++) { wg[s] = exp2f((mv[s] - M) * SCL); den += wg[s] * lv[s]; }
        float inv = 1.f / den;
        #pragma unroll
        for (int s = 0; s < SPLIT; s++) wg[s] *= inv;
        #pragma unroll
        for (int e = 0; e < 4; e++) {
            float accv[8];
            #pragma unroll
            for (int q = 0; q < 8; q++) accv[q] = 0.f;
            #pragma unroll
            for (int s = 0; s < SPLIT; s++) {
                u16x8 v = *(const u16x8*)(po + ((size_t)(s * NB + b) * NN + i) * NC + cq * 32 + e * 8);
                #pragma unroll
                for (int q = 0; q < 8; q++) accv[q] += wg[s] * b2f(v[q]);
            }
            u16x8 rv;
            #pragma unroll
            for (int q = 0; q < 8; q++) rv[q] = f2b(accv[q]);
            unsigned off = ((unsigned)(il * 512 + cq * 64 + e * 16)) ^ ((il & 7) << 4);
            *(u16x8*)((char*)Hs + off) = rv;
        }
    }
    __syncthreads();
    // GEMM: wave w owns o-range [w*64, +64); acc[4 mt][2 nt]
    f32x4 acc[4][2];
    #pragma unroll
    for (int mt = 0; mt < 4; mt++)
        #pragma unroll
        for (int nt = 0; nt < 2; nt++) acc[mt][nt] = (f32x4){0.f, 0.f, 0.f, 0.f};
    #pragma unroll
    for (int kk = 0; kk < 8; kk++) {
        bf16x8 bfr[2];
        #pragma unroll
        for (int nt = 0; nt < 2; nt++) {
            unsigned off = ((unsigned)((nt * 16 + (lane & 15)) * 512 + kk * 64 + ((lane >> 4) * 16)))
                           ^ (((unsigned)(lane & 7)) << 4);
            bfr[nt] = *(const bf16x8*)((char*)Hs + off);
        }
        #pragma unroll
        for (int mt = 0; mt < 4; mt++) {
            bf16x8 af = *(const bf16x8*)(wp_b + (size_t)(w * 64 + mt * 16 + (lane & 15)) * NC
                                         + kk * 32 + ((lane >> 4) * 8));
            #pragma unroll
            for (int nt = 0; nt < 2; nt++)
                acc[mt][nt] = __builtin_amdgcn_mfma_f32_16x16x32_bf16(af, bfr[nt], acc[mt][nt], 0, 0, 0);
        }
    }
    #pragma unroll
    for (int mt = 0; mt < 4; mt++) {
        #pragma unroll
        for (int r = 0; r < 4; r++) {
            int o = w * 64 + mt * 16 + (lane >> 4) * 4 + r;
            float bv_ = bp[o];
            #pragma unroll
            for (int nt = 0; nt < 2; nt++) {
                int i = i0 + nt * 16 + (lane & 15);
                size_t idx = ((size_t)b * NC + o) * NN + i;
                out[idx] = x[idx] + acc[mt][nt][r] + bv_;
            }
        }
    }
}

extern "C" void kernel_launch(void* const* d_in, const int* in_sizes, int n_in,
                              void* d_out, int out_size, void* d_ws, size_t ws_size,
                              hipStream_t stream) {
    const float* x     = (const float*)d_in[0];
    const float* gamma = (const float*)d_in[1];
    const float* beta  = (const float*)d_in[2];
    const float* wq    = (const float*)d_in[3];
    const float* bq    = (const float*)d_in[4];
    const float* wk    = (const float*)d_in[5];
    const float* bk    = (const float*)d_in[6];
    const float* wv    = (const float*)d_in[7];
    const float* bv    = (const float*)d_in[8];
    const float* wp    = (const float*)d_in[9];
    const float* bp    = (const float*)d_in[10];
    float* out = (float*)d_out;

    char* ws = (char*)d_ws;
    const size_t MB = 1024 * 1024;
    float*          stats = (float*)ws;                        // 1 KB (zeroed)
    unsigned short* wb    = (unsigned short*)(ws + 1024);      // 512 KB
    unsigned short* q_t   = (unsigned short*)(ws + 1 * MB);    // 4 MB
    unsigned short* k_t   = (unsigned short*)(ws + 5 * MB);    // 4 MB
    unsigned short* v_cm  = (unsigned short*)(ws + 9 * MB);    // 4 MB
    float*          ml    = (float*)(ws + 13 * MB);            // 512 KB
    unsigned short* hn_t  = (unsigned short*)(ws + 14 * MB);   // 4 MB (dead after k_qkv)
    unsigned short* po    = (unsigned short*)(ws + 14 * MB);   // 16 MB, aliases hn_t

    hipMemsetAsync(stats, 0, 1024, stream);
    k_wcvt<<<256, 256, 0, stream>>>(wq, wk, wv, wp, wb);
    k_stats<<<256, 256, 0, stream>>>(x, stats);
    k_norm_t<<<dim3(NN / 64, NC / 64, NB), 256, 0, stream>>>(x, gamma, beta, stats, hn_t);
    k_qkv<<<dim3(NN / 64, 3, NB), 256, 0, stream>>>(hn_t, wb, bq, bk, bv, q_t, k_t, v_cm);
    k_attn<<<256, 512, 0, stream>>>(q_t, k_t, v_cm, po, ml);
    k_proj<<<dim3(NN / 32, NB), 256, 0, stream>>>(po, ml, wb + 3 * 65536, bp, x, out);
}

// Round 8
// 211.345 us; speedup vs baseline: 2.4697x; 2.4697x over previous
//
#include <hip/hip_runtime.h>
#include <hip/hip_bf16.h>

#define NB 2
#define NC 256
#define NN 4096
#define NG 16
#define GSZ (16*NN)      // elements per (b,group) = 65536, contiguous in x
#define SPLIT 4
#define JT (NN / SPLIT / 64)   // j-tiles per split = 16
#define SCL 0.09014205f  // log2(e) / sqrt(256)
#define THRRAW 88.0f     // defer-max threshold in raw score units (~8/SCL)

typedef __attribute__((ext_vector_type(8))) short bf16x8;
typedef __attribute__((ext_vector_type(4))) float f32x4;
typedef __attribute__((ext_vector_type(8))) unsigned short u16x8;

static __device__ __forceinline__ unsigned short f2b(float f) {
    union { float f; unsigned u; } x; x.f = f;
    unsigned r = x.u + 0x7fffu + ((x.u >> 16) & 1u);
    return (unsigned short)(r >> 16);
}
static __device__ __forceinline__ float b2f(unsigned short u) {
    union { unsigned u; float f; } x; x.u = ((unsigned)u) << 16;
    return x.f;
}
// async global->LDS, 16B per lane; LDS dest must be wave-uniform base (+lane*16)
static __device__ __forceinline__ void glds16(const void* g, void* l) {
    __builtin_amdgcn_global_load_lds(
        (const __attribute__((address_space(1))) unsigned int*)g,
        (__attribute__((address_space(3))) unsigned int*)l, 16, 0, 0);
}

// ---------------- weights f32 -> bf16 (wq|wk|wv|wp) ----------------
__global__ void k_wcvt(const float* __restrict__ wq, const float* __restrict__ wk,
                       const float* __restrict__ wv, const float* __restrict__ wp,
                       unsigned short* __restrict__ dst) {
    int idx = (blockIdx.x * 256 + threadIdx.x) * 4;   // 0..262140
    int which = idx >> 16, off = idx & 65535;
    const float* s = (which == 0) ? wq : (which == 1) ? wk : (which == 2) ? wv : wp;
    float4 v = *(const float4*)(s + off);
    dst[idx + 0] = f2b(v.x);
    dst[idx + 1] = f2b(v.y);
    dst[idx + 2] = f2b(v.z);
    dst[idx + 3] = f2b(v.w);
}

// ---------------- group-norm sums: 8 blocks per (b,g), atomic accumulate ----------------
__global__ void k_stats(const float* __restrict__ x, float* __restrict__ stats) {
    int bg = blockIdx.x >> 3, seg = blockIdx.x & 7;   // 32 groups x 8 segments
    const float4* p = (const float4*)(x + (size_t)bg * GSZ + (size_t)seg * (GSZ / 8));
    float s1 = 0.f, s2 = 0.f;
    for (int k = threadIdx.x; k < GSZ / 8 / 4; k += 256) {
        float4 v = p[k];
        s1 += v.x + v.y + v.z + v.w;
        s2 += v.x*v.x + v.y*v.y + v.z*v.z + v.w*v.w;
    }
    #pragma unroll
    for (int m = 1; m < 64; m <<= 1) { s1 += __shfl_xor(s1, m); s2 += __shfl_xor(s2, m); }
    __shared__ float r1[4], r2[4];
    int w = threadIdx.x >> 6;
    if ((threadIdx.x & 63) == 0) { r1[w] = s1; r2[w] = s2; }
    __syncthreads();
    if (threadIdx.x == 0) {
        float a = 0.f, b = 0.f;
        #pragma unroll
        for (int i = 0; i < 4; i++) { a += r1[i]; b += r2[i]; }
        atomicAdd(&stats[bg * 2], a);
        atomicAdd(&stats[bg * 2 + 1], b);
    }
}

// ---------------- normalize + transpose -> hn_t[b][n][c] bf16 ----------------
__global__ void k_norm_t(const float* __restrict__ x, const float* __restrict__ gamma,
                         const float* __restrict__ beta, const float* __restrict__ stats,
                         unsigned short* __restrict__ hn_t) {
    __shared__ unsigned short tile[64][66];
    int n0 = blockIdx.x * 64, c0 = blockIdx.y * 64, b = blockIdx.z;
    int cc = threadIdx.x >> 2, part = threadIdx.x & 3;
    int c = c0 + cc;
    float s1 = stats[(b * NG + (c >> 4)) * 2];
    float s2 = stats[(b * NG + (c >> 4)) * 2 + 1];
    float mean = s1 * (1.f / (float)GSZ);
    float var  = s2 * (1.f / (float)GSZ) - mean * mean;
    float rstd = rsqrtf(var + 1e-6f);
    float sc = rstd * gamma[c];
    float sh = beta[c] - mean * sc;
    const float4* row = (const float4*)(x + ((size_t)b * NC + c) * NN + n0);
    #pragma unroll
    for (int q = 0; q < 4; q++) {
        int f4 = part * 4 + q;
        float4 v = row[f4];
        tile[cc][f4*4+0] = f2b(v.x * sc + sh);
        tile[cc][f4*4+1] = f2b(v.y * sc + sh);
        tile[cc][f4*4+2] = f2b(v.z * sc + sh);
        tile[cc][f4*4+3] = f2b(v.w * sc + sh);
    }
    __syncthreads();
    int nn = threadIdx.x >> 2;
    u16x8 o0, o1;
    #pragma unroll
    for (int e = 0; e < 8; e++) { o0[e] = tile[part*16 + e][nn]; o1[e] = tile[part*16 + 8 + e][nn]; }
    unsigned short* dst = hn_t + ((size_t)b * NN + n0 + nn) * NC + c0 + part * 16;
    *(u16x8*)dst = o0;
    *(u16x8*)(dst + 8) = o1;
}

// ---------------- QKV GEMM ----------------
// q,k: C[i][o] -> q_t/k_t[b][i][c].  v: operand-swapped C[o][i] -> v_cm[b][c][n].
__global__ __launch_bounds__(256, 2) void k_qkv(
        const unsigned short* __restrict__ hn_t, const unsigned short* __restrict__ wb,
        const float* __restrict__ bq, const float* __restrict__ bk, const float* __restrict__ bv,
        unsigned short* __restrict__ q_t, unsigned short* __restrict__ k_t,
        unsigned short* __restrict__ v_cm) {
    int i0 = blockIdx.x * 64, which = blockIdx.y, b = blockIdx.z;
    int lane = threadIdx.x & 63, w = threadIdx.x >> 6;
    const unsigned short* W = wb + which * 65536;
    const float* bias = (which == 0) ? bq : (which == 1) ? bk : bv;
    if (which < 2) {
        const unsigned short* arow =
            hn_t + ((size_t)b * NN + i0 + w * 16 + (lane & 15)) * NC + ((lane >> 4) * 8);
        f32x4 acc[16];
        #pragma unroll
        for (int t = 0; t < 16; t++) acc[t] = (f32x4){0.f, 0.f, 0.f, 0.f};
        #pragma unroll
        for (int kk = 0; kk < 8; kk++) {
            bf16x8 af = *(const bf16x8*)(arow + kk * 32);
            const unsigned short* bbase = W + (size_t)(lane & 15) * NC + kk * 32 + ((lane >> 4) * 8);
            #pragma unroll
            for (int ot = 0; ot < 16; ot++) {
                bf16x8 bf_ = *(const bf16x8*)(bbase + (size_t)ot * 16 * NC);
                acc[ot] = __builtin_amdgcn_mfma_f32_16x16x32_bf16(af, bf_, acc[ot], 0, 0, 0);
            }
        }
        unsigned short* dst = ((which == 0) ? q_t : k_t) + (size_t)b * NN * NC;
        #pragma unroll
        for (int ot = 0; ot < 16; ot++) {
            float bv_ = bias[ot * 16 + (lane & 15)];
            #pragma unroll
            for (int r = 0; r < 4; r++) {
                int i = i0 + w * 16 + (lane >> 4) * 4 + r;
                dst[(size_t)i * NC + ot * 16 + (lane & 15)] = f2b(acc[ot][r] + bv_);
            }
        }
    } else {
        // wave w owns o-range [w*64, +64); C[o][i] = sum_c wv[o][c] hn[i][c]
        f32x4 acc[4][4];
        #pragma unroll
        for (int mt = 0; mt < 4; mt++)
            #pragma unroll
            for (int nt = 0; nt < 4; nt++) acc[mt][nt] = (f32x4){0.f, 0.f, 0.f, 0.f};
        #pragma unroll
        for (int kk = 0; kk < 8; kk++) {
            bf16x8 bfr[4];
            #pragma unroll
            for (int nt = 0; nt < 4; nt++)
                bfr[nt] = *(const bf16x8*)(hn_t + ((size_t)b * NN + i0 + nt * 16 + (lane & 15)) * NC
                                           + kk * 32 + ((lane >> 4) * 8));
            #pragma unroll
            for (int mt = 0; mt < 4; mt++) {
                bf16x8 af = *(const bf16x8*)(W + (size_t)(w * 64 + mt * 16 + (lane & 15)) * NC
                                             + kk * 32 + ((lane >> 4) * 8));
                #pragma unroll
                for (int nt = 0; nt < 4; nt++)
                    acc[mt][nt] = __builtin_amdgcn_mfma_f32_16x16x32_bf16(af, bfr[nt], acc[mt][nt], 0, 0, 0);
            }
        }
        #pragma unroll
        for (int mt = 0; mt < 4; mt++) {
            #pragma unroll
            for (int r = 0; r < 4; r++) {
                int o = w * 64 + mt * 16 + (lane >> 4) * 4 + r;
                float bv_ = bias[o];
                #pragma unroll
                for (int nt = 0; nt < 4; nt++) {
                    int i = i0 + nt * 16 + (lane & 15);
                    v_cm[(size_t)b * NC * NN + (size_t)o * NN + i] = f2b(acc[mt][nt][r] + bv_);
                }
            }
        }
    }
}

// ---------------- flash attention: 8 waves x 16 i-rows, K+V dbuf glds, defer-max ----
// grid 256: bid&7 -> (sp,b) (XCD-grouped), bid>>3 -> i-block (128 rows).
// NOTE: never bound above 2 waves/SIMD here — o[16]+qf[8] needs ~190 unified regs (r5/r7).
__global__ __launch_bounds__(512, 2) void k_attn(
        const unsigned short* __restrict__ q_t, const unsigned short* __restrict__ k_t,
        const unsigned short* __restrict__ v_cm,
        unsigned short* __restrict__ po, float* __restrict__ ml) {
    __shared__ __attribute__((aligned(16))) unsigned short Ks[2][16384]; // [j 64][c 256] swz
    __shared__ __attribute__((aligned(16))) unsigned short Vs[2][16384]; // [c 256][j 64] swz
    __shared__ __attribute__((aligned(16))) unsigned short Ps[8][1024];  // [i 16][j 64] swz
    int bid = blockIdx.x;
    int g = bid & 7, xb = bid >> 3;
    int sp = g & 3, b = g >> 2;
    int i0 = xb * 128;
    int lane = threadIdx.x & 63, w = threadIdx.x >> 6;
    size_t bO = (size_t)b * NN * NC;
    // Q fragments (wave w owns rows i0+w*16 .. +16)
    bf16x8 qf[8];
    {
        const unsigned short* qrow =
            q_t + bO + (size_t)(i0 + w * 16 + (lane & 15)) * NC + ((lane >> 4) * 8);
        #pragma unroll
        for (int kk = 0; kk < 8; kk++) qf[kk] = *(const bf16x8*)(qrow + kk * 32);
    }
    // per-lane pre-swizzled global source offsets (linear LDS dest -> inverse-swz source)
    unsigned kstat[4], vstat[4];
    #pragma unroll
    for (int r = 0; r < 4; r++) {
        int jr = r * 16 + w * 2 + (lane >> 5);
        kstat[r] = (unsigned)(jr * 512 + (((lane & 31) * 16) ^ ((jr & 7) << 4)));
        int cr = r * 64 + w * 8 + (lane >> 3);
        vstat[r] = (unsigned)(cr * 8192 + (((lane & 7) * 16) ^ ((cr & 7) << 4)));
    }
    const char* kp = (const char*)(k_t + bO) + (size_t)sp * 524288;  // sp*1024 rows * 512B
    const char* vp = (const char*)(v_cm + bO) + (size_t)sp * 2048;   // sp*1024 j * 2B
    f32x4 o[16];
    #pragma unroll
    for (int t = 0; t < 16; t++) o[t] = (f32x4){0.f, 0.f, 0.f, 0.f};
    float m[4], l[4];
    #pragma unroll
    for (int r = 0; r < 4; r++) { m[r] = -1e30f; l[r] = 0.f; }
    // prologue: stage tile 0 into buf 0
    #pragma unroll
    for (int r = 0; r < 4; r++) {
        glds16(kp + kstat[r], (char*)&Ks[0][0] + w * 1024 + r * 8192);
        glds16(vp + vstat[r], (char*)&Vs[0][0] + w * 1024 + r * 8192);
    }
    __syncthreads();
    int cur = 0;
    #pragma unroll 1
    for (int t = 0; t < JT; ++t) {
        if (t < JT - 1) {   // issue next-tile staging into alt buffer (overlaps compute)
            kp += 32768; vp += 128;
            int nb = cur ^ 1;
            #pragma unroll
            for (int r = 0; r < 4; r++) {
                glds16(kp + kstat[r], (char*)&Ks[nb][0] + w * 1024 + r * 8192);
                glds16(vp + vstat[r], (char*)&Vs[nb][0] + w * 1024 + r * 8192);
            }
        }
        const char* KsB = (const char*)&Ks[cur][0];
        const char* VsB = (const char*)&Vs[cur][0];
        // S = Q K^T
        f32x4 s[4];
        #pragma unroll
        for (int tt = 0; tt < 4; tt++) s[tt] = (f32x4){0.f, 0.f, 0.f, 0.f};
        __builtin_amdgcn_s_setprio(1);
        #pragma unroll
        for (int kk = 0; kk < 8; kk++) {
            #pragma unroll
            for (int tt = 0; tt < 4; tt++) {
                unsigned off = ((unsigned)((tt * 16 + (lane & 15)) * 512 + kk * 64 + ((lane >> 4) * 16)))
                               ^ (((unsigned)(lane & 7)) << 4);
                bf16x8 kf = *(const bf16x8*)(KsB + off);
                s[tt] = __builtin_amdgcn_mfma_f32_16x16x32_bf16(qf[kk], kf, s[tt], 0, 0, 0);
            }
        }
        __builtin_amdgcn_s_setprio(0);
        // online softmax with deferred rescale (T13)
        float vmax[4];
        #pragma unroll
        for (int r = 0; r < 4; r++) {
            float v0 = fmaxf(fmaxf(s[0][r], s[1][r]), fmaxf(s[2][r], s[3][r]));
            v0 = fmaxf(v0, __shfl_xor(v0, 1));
            v0 = fmaxf(v0, __shfl_xor(v0, 2));
            v0 = fmaxf(v0, __shfl_xor(v0, 4));
            v0 = fmaxf(v0, __shfl_xor(v0, 8));
            vmax[r] = v0;
        }
        float tmax = fmaxf(fmaxf(vmax[0] - m[0], vmax[1] - m[1]),
                           fmaxf(vmax[2] - m[2], vmax[3] - m[3]));
        tmax = fmaxf(tmax, __shfl_xor(tmax, 16));
        tmax = fmaxf(tmax, __shfl_xor(tmax, 32));
        if (tmax > THRRAW) {    // wave-uniform rescale (rare: ~1 of 16 tiles)
            #pragma unroll
            for (int r = 0; r < 4; r++) {
                float mn = fmaxf(m[r], vmax[r]);
                float corr = exp2f((m[r] - mn) * SCL);
                m[r] = mn;
                l[r] *= corr;
                #pragma unroll
                for (int ct = 0; ct < 16; ct++) o[ct][r] *= corr;
            }
        }
        float rs[4] = {0.f, 0.f, 0.f, 0.f};
        #pragma unroll
        for (int tt = 0; tt < 4; tt++) {
            #pragma unroll
            for (int r = 0; r < 4; r++) {
                float p = exp2f((s[tt][r] - m[r]) * SCL);
                rs[r] += p;
                unsigned i_ = (unsigned)((lane >> 4) * 4 + r);
                unsigned off = ((unsigned)(i_ * 128 + (tt * 16 + (lane & 15)) * 2)) ^ ((i_ & 7) << 4);
                *(unsigned short*)((char*)&Ps[w][0] + off) = f2b(p);
            }
        }
        #pragma unroll
        for (int r = 0; r < 4; r++) {
            float v0 = rs[r];
            v0 += __shfl_xor(v0, 1); v0 += __shfl_xor(v0, 2);
            v0 += __shfl_xor(v0, 4); v0 += __shfl_xor(v0, 8);
            l[r] += v0;
        }
        // O += P V (wave-local P; no barrier needed)
        __builtin_amdgcn_s_setprio(1);
        #pragma unroll
        for (int kk = 0; kk < 2; kk++) {
            unsigned offp = ((unsigned)((lane & 15) * 128 + kk * 64 + ((lane >> 4) * 16)))
                            ^ (((unsigned)(lane & 7)) << 4);
            bf16x8 pf = *(const bf16x8*)((char*)&Ps[w][0] + offp);
            #pragma unroll
            for (int ct = 0; ct < 16; ct++) {
                unsigned offv = ((unsigned)((ct * 16 + (lane & 15)) * 128 + kk * 64 + ((lane >> 4) * 16)))
                                ^ (((unsigned)(lane & 7)) << 4);
                bf16x8 vf = *(const bf16x8*)(VsB + offv);
                o[ct] = __builtin_amdgcn_mfma_f32_16x16x32_bf16(pf, vf, o[ct], 0, 0, 0);
            }
        }
        __builtin_amdgcn_s_setprio(0);
        __syncthreads();   // drains glds (vmcnt) + protects buffer reuse
        cur ^= 1;
    }
    // write unnormalized partial O and (m, l)
    unsigned short* dst = po + (size_t)(sp * NB + b) * NN * NC;
    #pragma unroll
    for (int ct = 0; ct < 16; ct++) {
        #pragma unroll
        for (int r = 0; r < 4; r++) {
            int i = i0 + w * 16 + (lane >> 4) * 4 + r;
            dst[(size_t)i * NC + ct * 16 + (lane & 15)] = f2b(o[ct][r]);
        }
    }
    if ((lane & 15) == 0) {
        #pragma unroll
        for (int r = 0; r < 4; r++) {
            int i = i0 + w * 16 + (lane >> 4) * 4 + r;
            size_t mi = ((size_t)(sp * NB + b) * NN + i) * 2;
            ml[mi] = m[r];
            ml[mi + 1] = l[r];
        }
    }
}

// ---------------- fused combine + projection + residual ----------------
// block: i-tile 32, all 256 o. C[o][i] = sum_c wp[o][c] ho[i][c]; out = x + C + bp.
__global__ __launch_bounds__(256, 4) void k_proj(
        const unsigned short* __restrict__ po, const float* __restrict__ ml,
        const unsigned short* __restrict__ wp_b, const float* __restrict__ bp,
        const float* __restrict__ x, float* __restrict__ out) {
    __shared__ __attribute__((aligned(16))) unsigned short Hs[32 * 256]; // [i 32][c 256] swz
    int i0 = blockIdx.x * 32, b = blockIdx.y;
    int tid = threadIdx.x, lane = tid & 63, w = tid >> 6;
    {   // combine SPLIT splits -> Hs (combine weights computed inline)
        int il = tid >> 3, cq = tid & 7;
        int i = i0 + il;
        float mv[SPLIT], lv[SPLIT];
        float M = -1e30f;
        #pragma unroll
        for (int s = 0; s < SPLIT; s++) {
            size_t mi = ((size_t)(s * NB + b) * NN + i) * 2;
            mv[s] = ml[mi]; lv[s] = ml[mi + 1];
            M = fmaxf(M, mv[s]);
        }
        float den = 0.f, wg[SPLIT];
        #pragma unroll
        for (int s = 0; s < SPLIT; s++) { wg[s] = exp2f((mv[s] - M) * SCL); den += wg[s] * lv[s]; }
        float inv = 1.f / den;
        #pragma unroll
        for (int s = 0; s < SPLIT; s++) wg[s] *= inv;
        #pragma unroll
        for (int e = 0; e < 4; e++) {
            float accv[8];
            #pragma unroll
            for (int q = 0; q < 8; q++) accv[q] = 0.f;
            #pragma unroll
            for (int s = 0; s < SPLIT; s++) {
                u16x8 v = *(const u16x8*)(po + ((size_t)(s * NB + b) * NN + i) * NC + cq * 32 + e * 8);
                #pragma unroll
                for (int q = 0; q < 8; q++) accv[q] += wg[s] * b2f(v[q]);
            }
            u16x8 rv;
            #pragma unroll
            for (int q = 0; q < 8; q++) rv[q] = f2b(accv[q]);
            unsigned off = ((unsigned)(il * 512 + cq * 64 + e * 16)) ^ ((il & 7) << 4);
            *(u16x8*)((char*)Hs + off) = rv;
        }
    }
    __syncthreads();
    // GEMM: wave w owns o-range [w*64, +64); acc[4 mt][2 nt]
    f32x4 acc[4][2];
    #pragma unroll
    for (int mt = 0; mt < 4; mt++)
        #pragma unroll
        for (int nt = 0; nt < 2; nt++) acc[mt][nt] = (f32x4){0.f, 0.f, 0.f, 0.f};
    #pragma unroll
    for (int kk = 0; kk < 8; kk++) {
        bf16x8 bfr[2];
        #pragma unroll
        for (int nt = 0; nt < 2; nt++) {
            unsigned off = ((unsigned)((nt * 16 + (lane & 15)) * 512 + kk * 64 + ((lane >> 4) * 16)))
                           ^ (((unsigned)(lane & 7)) << 4);
            bfr[nt] = *(const bf16x8*)((char*)Hs + off);
        }
        #pragma unroll
        for (int mt = 0; mt < 4; mt++) {
            bf16x8 af = *(const bf16x8*)(wp_b + (size_t)(w * 64 + mt * 16 + (lane & 15)) * NC
                                         + kk * 32 + ((lane >> 4) * 8));
            #pragma unroll
            for (int nt = 0; nt < 2; nt++)
                acc[mt][nt] = __builtin_amdgcn_mfma_f32_16x16x32_bf16(af, bfr[nt], acc[mt][nt], 0, 0, 0);
        }
    }
    #pragma unroll
    for (int mt = 0; mt < 4; mt++) {
        #pragma unroll
        for (int r = 0; r < 4; r++) {
            int o = w * 64 + mt * 16 + (lane >> 4) * 4 + r;
            float bv_ = bp[o];
            #pragma unroll
            for (int nt = 0; nt < 2; nt++) {
                int i = i0 + nt * 16 + (lane & 15);
                size_t idx = ((size_t)b * NC + o) * NN + i;
                out[idx] = x[idx] + acc[mt][nt][r] + bv_;
            }
        }
    }
}

extern "C" void kernel_launch(void* const* d_in, const int* in_sizes, int n_in,
                              void* d_out, int out_size, void* d_ws, size_t ws_size,
                              hipStream_t stream) {
    const float* x     = (const float*)d_in[0];
    const float* gamma = (const float*)d_in[1];
    const float* beta  = (const float*)d_in[2];
    const float* wq    = (const float*)d_in[3];
    const float* bq    = (const float*)d_in[4];
    const float* wk    = (const float*)d_in[5];
    const float* bk    = (const float*)d_in[6];
    const float* wv    = (const float*)d_in[7];
    const float* bv    = (const float*)d_in[8];
    const float* wp    = (const float*)d_in[9];
    const float* bp    = (const float*)d_in[10];
    float* out = (float*)d_out;

    char* ws = (char*)d_ws;
    const size_t MB = 1024 * 1024;
    float*          stats = (float*)ws;                        // 1 KB (zeroed)
    unsigned short* wb    = (unsigned short*)(ws + 1024);      // 512 KB
    unsigned short* q_t   = (unsigned short*)(ws + 1 * MB);    // 4 MB
    unsigned short* k_t   = (unsigned short*)(ws + 5 * MB);    // 4 MB
    unsigned short* v_cm  = (unsigned short*)(ws + 9 * MB);    // 4 MB
    float*          ml    = (float*)(ws + 13 * MB);            // 512 KB
    unsigned short* hn_t  = (unsigned short*)(ws + 14 * MB);   // 4 MB (dead after k_qkv)
    unsigned short* po    = (unsigned short*)(ws + 14 * MB);   // 16 MB, aliases hn_t

    hipMemsetAsync(stats, 0, 1024, stream);
    k_wcvt<<<256, 256, 0, stream>>>(wq, wk, wv, wp, wb);
    k_stats<<<256, 256, 0, stream>>>(x, stats);
    k_norm_t<<<dim3(NN / 64, NC / 64, NB), 256, 0, stream>>>(x, gamma, beta, stats, hn_t);
    k_qkv<<<dim3(NN / 64, 3, NB), 256, 0, stream>>>(hn_t, wb, bq, bk, bv, q_t, k_t, v_cm);
    k_attn<<<256, 512, 0, stream>>>(q_t, k_t, v_cm, po, ml);
    k_proj<<<dim3(NN / 32, NB), 256, 0, stream>>>(po, ml, wb + 3 * 65536, bp, x, out);
}

// Round 9
// 203.266 us; speedup vs baseline: 2.5679x; 1.0397x over previous
//
#include <hip/hip_runtime.h>
#include <hip/hip_bf16.h>

#define NB 2
#define NC 256
#define NN 4096
#define NG 16
#define GSZ (16*NN)      // elements per (b,group) = 65536, contiguous in x
#define SPLIT 4
#define JT (NN / SPLIT / 64)   // j-tiles per split = 16
#define SCL 0.09014205f  // log2(e) / sqrt(256)
#define THRRAW 88.0f     // defer-max threshold in raw score units (~8/SCL)

typedef __attribute__((ext_vector_type(8))) short bf16x8;
typedef __attribute__((ext_vector_type(4))) float f32x4;
typedef __attribute__((ext_vector_type(8))) unsigned short u16x8;

static __device__ __forceinline__ unsigned short f2b(float f) {
    union { float f; unsigned u; } x; x.f = f;
    unsigned r = x.u + 0x7fffu + ((x.u >> 16) & 1u);
    return (unsigned short)(r >> 16);
}
static __device__ __forceinline__ float b2f(unsigned short u) {
    union { unsigned u; float f; } x; x.u = ((unsigned)u) << 16;
    return x.f;
}
// async global->LDS, 16B per lane; LDS dest must be wave-uniform base (+lane*16)
static __device__ __forceinline__ void glds16(const void* g, void* l) {
    __builtin_amdgcn_global_load_lds(
        (const __attribute__((address_space(1))) unsigned int*)g,
        (__attribute__((address_space(3))) unsigned int*)l, 16, 0, 0);
}

// ---------------- weights f32 -> bf16 (wq|wk|wv|wp) ----------------
__global__ void k_wcvt(const float* __restrict__ wq, const float* __restrict__ wk,
                       const float* __restrict__ wv, const float* __restrict__ wp,
                       unsigned short* __restrict__ dst) {
    int idx = (blockIdx.x * 256 + threadIdx.x) * 4;   // 0..262140
    int which = idx >> 16, off = idx & 65535;
    const float* s = (which == 0) ? wq : (which == 1) ? wk : (which == 2) ? wv : wp;
    float4 v = *(const float4*)(s + off);
    dst[idx + 0] = f2b(v.x);
    dst[idx + 1] = f2b(v.y);
    dst[idx + 2] = f2b(v.z);
    dst[idx + 3] = f2b(v.w);
}

// ---------------- group-norm sums: 8 blocks per (b,g), atomic accumulate ----------------
__global__ void k_stats(const float* __restrict__ x, float* __restrict__ stats) {
    int bg = blockIdx.x >> 3, seg = blockIdx.x & 7;   // 32 groups x 8 segments
    const float4* p = (const float4*)(x + (size_t)bg * GSZ + (size_t)seg * (GSZ / 8));
    float s1 = 0.f, s2 = 0.f;
    for (int k = threadIdx.x; k < GSZ / 8 / 4; k += 256) {
        float4 v = p[k];
        s1 += v.x + v.y + v.z + v.w;
        s2 += v.x*v.x + v.y*v.y + v.z*v.z + v.w*v.w;
    }
    #pragma unroll
    for (int m = 1; m < 64; m <<= 1) { s1 += __shfl_xor(s1, m); s2 += __shfl_xor(s2, m); }
    __shared__ float r1[4], r2[4];
    int w = threadIdx.x >> 6;
    if ((threadIdx.x & 63) == 0) { r1[w] = s1; r2[w] = s2; }
    __syncthreads();
    if (threadIdx.x == 0) {
        float a = 0.f, b = 0.f;
        #pragma unroll
        for (int i = 0; i < 4; i++) { a += r1[i]; b += r2[i]; }
        atomicAdd(&stats[bg * 2], a);
        atomicAdd(&stats[bg * 2 + 1], b);
    }
}

// ---------------- normalize + transpose -> hn_t[b][n][c] bf16 ----------------
__global__ void k_norm_t(const float* __restrict__ x, const float* __restrict__ gamma,
                         const float* __restrict__ beta, const float* __restrict__ stats,
                         unsigned short* __restrict__ hn_t) {
    __shared__ unsigned short tile[64][66];
    int n0 = blockIdx.x * 64, c0 = blockIdx.y * 64, b = blockIdx.z;
    int cc = threadIdx.x >> 2, part = threadIdx.x & 3;
    int c = c0 + cc;
    float s1 = stats[(b * NG + (c >> 4)) * 2];
    float s2 = stats[(b * NG + (c >> 4)) * 2 + 1];
    float mean = s1 * (1.f / (float)GSZ);
    float var  = s2 * (1.f / (float)GSZ) - mean * mean;
    float rstd = rsqrtf(var + 1e-6f);
    float sc = rstd * gamma[c];
    float sh = beta[c] - mean * sc;
    const float4* row = (const float4*)(x + ((size_t)b * NC + c) * NN + n0);
    #pragma unroll
    for (int q = 0; q < 4; q++) {
        int f4 = part * 4 + q;
        float4 v = row[f4];
        tile[cc][f4*4+0] = f2b(v.x * sc + sh);
        tile[cc][f4*4+1] = f2b(v.y * sc + sh);
        tile[cc][f4*4+2] = f2b(v.z * sc + sh);
        tile[cc][f4*4+3] = f2b(v.w * sc + sh);
    }
    __syncthreads();
    int nn = threadIdx.x >> 2;
    u16x8 o0, o1;
    #pragma unroll
    for (int e = 0; e < 8; e++) { o0[e] = tile[part*16 + e][nn]; o1[e] = tile[part*16 + 8 + e][nn]; }
    unsigned short* dst = hn_t + ((size_t)b * NN + n0 + nn) * NC + c0 + part * 16;
    *(u16x8*)dst = o0;
    *(u16x8*)(dst + 8) = o1;
}

// ---------------- QKV GEMM ----------------
// q,k: C[i][o] -> q_t/k_t[b][i][c].  v: operand-swapped C[o][i] -> v_cm[b][c][n].
__global__ __launch_bounds__(256, 2) void k_qkv(
        const unsigned short* __restrict__ hn_t, const unsigned short* __restrict__ wb,
        const float* __restrict__ bq, const float* __restrict__ bk, const float* __restrict__ bv,
        unsigned short* __restrict__ q_t, unsigned short* __restrict__ k_t,
        unsigned short* __restrict__ v_cm) {
    int i0 = blockIdx.x * 64, which = blockIdx.y, b = blockIdx.z;
    int lane = threadIdx.x & 63, w = threadIdx.x >> 6;
    const unsigned short* W = wb + which * 65536;
    const float* bias = (which == 0) ? bq : (which == 1) ? bk : bv;
    if (which < 2) {
        const unsigned short* arow =
            hn_t + ((size_t)b * NN + i0 + w * 16 + (lane & 15)) * NC + ((lane >> 4) * 8);
        f32x4 acc[16];
        #pragma unroll
        for (int t = 0; t < 16; t++) acc[t] = (f32x4){0.f, 0.f, 0.f, 0.f};
        #pragma unroll
        for (int kk = 0; kk < 8; kk++) {
            bf16x8 af = *(const bf16x8*)(arow + kk * 32);
            const unsigned short* bbase = W + (size_t)(lane & 15) * NC + kk * 32 + ((lane >> 4) * 8);
            #pragma unroll
            for (int ot = 0; ot < 16; ot++) {
                bf16x8 bf_ = *(const bf16x8*)(bbase + (size_t)ot * 16 * NC);
                acc[ot] = __builtin_amdgcn_mfma_f32_16x16x32_bf16(af, bf_, acc[ot], 0, 0, 0);
            }
        }
        unsigned short* dst = ((which == 0) ? q_t : k_t) + (size_t)b * NN * NC;
        #pragma unroll
        for (int ot = 0; ot < 16; ot++) {
            float bv_ = bias[ot * 16 + (lane & 15)];
            #pragma unroll
            for (int r = 0; r < 4; r++) {
                int i = i0 + w * 16 + (lane >> 4) * 4 + r;
                dst[(size_t)i * NC + ot * 16 + (lane & 15)] = f2b(acc[ot][r] + bv_);
            }
        }
    } else {
        // wave w owns o-range [w*64, +64); C[o][i] = sum_c wv[o][c] hn[i][c]
        f32x4 acc[4][4];
        #pragma unroll
        for (int mt = 0; mt < 4; mt++)
            #pragma unroll
            for (int nt = 0; nt < 4; nt++) acc[mt][nt] = (f32x4){0.f, 0.f, 0.f, 0.f};
        #pragma unroll
        for (int kk = 0; kk < 8; kk++) {
            bf16x8 bfr[4];
            #pragma unroll
            for (int nt = 0; nt < 4; nt++)
                bfr[nt] = *(const bf16x8*)(hn_t + ((size_t)b * NN + i0 + nt * 16 + (lane & 15)) * NC
                                           + kk * 32 + ((lane >> 4) * 8));
            #pragma unroll
            for (int mt = 0; mt < 4; mt++) {
                bf16x8 af = *(const bf16x8*)(W + (size_t)(w * 64 + mt * 16 + (lane & 15)) * NC
                                             + kk * 32 + ((lane >> 4) * 8));
                #pragma unroll
                for (int nt = 0; nt < 4; nt++)
                    acc[mt][nt] = __builtin_amdgcn_mfma_f32_16x16x32_bf16(af, bfr[nt], acc[mt][nt], 0, 0, 0);
            }
        }
        #pragma unroll
        for (int mt = 0; mt < 4; mt++) {
            #pragma unroll
            for (int r = 0; r < 4; r++) {
                int o = w * 64 + mt * 16 + (lane >> 4) * 4 + r;
                float bv_ = bias[o];
                #pragma unroll
                for (int nt = 0; nt < 4; nt++) {
                    int i = i0 + nt * 16 + (lane & 15);
                    v_cm[(size_t)b * NC * NN + (size_t)o * NN + i] = f2b(acc[mt][nt][r] + bv_);
                }
            }
        }
    }
}

// ---------------- flash attention: 8 waves x 16 i-rows, K+V dbuf glds, defer-max ----
// SWAPPED QK^T: S computed as mfma(K,Q) so lane holds S[i=lane&15][j-subset] ->
// in-lane softmax reductions (VALU, not LDS shuffles) + b64-packed P writes.
// grid 256: bid&7 -> (sp,b) (XCD-grouped), bid>>3 -> i-block (128 rows).
// NOTE: never bound above 2 waves/SIMD here — o[16]+qf[8] needs ~190 unified regs (r5/r7).
__global__ __launch_bounds__(512, 2) void k_attn(
        const unsigned short* __restrict__ q_t, const unsigned short* __restrict__ k_t,
        const unsigned short* __restrict__ v_cm,
        unsigned short* __restrict__ po, float* __restrict__ ml) {
    __shared__ __attribute__((aligned(16))) unsigned short Ks[2][16384]; // [j 64][c 256] swz
    __shared__ __attribute__((aligned(16))) unsigned short Vs[2][16384]; // [c 256][j 64] swz
    __shared__ __attribute__((aligned(16))) unsigned short Ps[8][1024];  // [i 16][j 64] swz
    int bid = blockIdx.x;
    int g = bid & 7, xb = bid >> 3;
    int sp = g & 3, b = g >> 2;
    int i0 = xb * 128;
    int lane = threadIdx.x & 63, w = threadIdx.x >> 6;
    size_t bO = (size_t)b * NN * NC;
    // Q fragments (wave w owns rows i0+w*16 .. +16); used as MFMA B-operand
    bf16x8 qf[8];
    {
        const unsigned short* qrow =
            q_t + bO + (size_t)(i0 + w * 16 + (lane & 15)) * NC + ((lane >> 4) * 8);
        #pragma unroll
        for (int kk = 0; kk < 8; kk++) qf[kk] = *(const bf16x8*)(qrow + kk * 32);
    }
    // per-lane pre-swizzled global source offsets (linear LDS dest -> inverse-swz source)
    unsigned kstat[4], vstat[4];
    #pragma unroll
    for (int r = 0; r < 4; r++) {
        int jr = r * 16 + w * 2 + (lane >> 5);
        kstat[r] = (unsigned)(jr * 512 + (((lane & 31) * 16) ^ ((jr & 7) << 4)));
        int cr = r * 64 + w * 8 + (lane >> 3);
        vstat[r] = (unsigned)(cr * 8192 + (((lane & 7) * 16) ^ ((cr & 7) << 4)));
    }
    const char* kp = (const char*)(k_t + bO) + (size_t)sp * 524288;  // sp*1024 rows * 512B
    const char* vp = (const char*)(v_cm + bO) + (size_t)sp * 2048;   // sp*1024 j * 2B
    f32x4 o[16];
    #pragma unroll
    for (int t = 0; t < 16; t++) o[t] = (f32x4){0.f, 0.f, 0.f, 0.f};
    float m = -1e30f, l = 0.f;   // per-lane: row i = lane&15
    // prologue: stage tile 0 into buf 0
    #pragma unroll
    for (int r = 0; r < 4; r++) {
        glds16(kp + kstat[r], (char*)&Ks[0][0] + w * 1024 + r * 8192);
        glds16(vp + vstat[r], (char*)&Vs[0][0] + w * 1024 + r * 8192);
    }
    __syncthreads();
    int cur = 0;
    #pragma unroll 1
    for (int t = 0; t < JT; ++t) {
        if (t < JT - 1) {   // issue next-tile staging into alt buffer (overlaps compute)
            kp += 32768; vp += 128;
            int nb = cur ^ 1;
            #pragma unroll
            for (int r = 0; r < 4; r++) {
                glds16(kp + kstat[r], (char*)&Ks[nb][0] + w * 1024 + r * 8192);
                glds16(vp + vstat[r], (char*)&Vs[nb][0] + w * 1024 + r * 8192);
            }
        }
        const char* KsB = (const char*)&Ks[cur][0];
        const char* VsB = (const char*)&Vs[cur][0];
        // S^T tiles: mfma(A=K j-rows, B=Q i-cols) -> lane holds
        // S[i=lane&15][j = tt*16 + (lane>>4)*4 + r]
        f32x4 s[4];
        #pragma unroll
        for (int tt = 0; tt < 4; tt++) s[tt] = (f32x4){0.f, 0.f, 0.f, 0.f};
        __builtin_amdgcn_s_setprio(1);
        #pragma unroll
        for (int kk = 0; kk < 8; kk++) {
            #pragma unroll
            for (int tt = 0; tt < 4; tt++) {
                unsigned off = ((unsigned)((tt * 16 + (lane & 15)) * 512 + kk * 64 + ((lane >> 4) * 16)))
                               ^ (((unsigned)(lane & 7)) << 4);
                bf16x8 kf = *(const bf16x8*)(KsB + off);
                s[tt] = __builtin_amdgcn_mfma_f32_16x16x32_bf16(kf, qf[kk], s[tt], 0, 0, 0);
            }
        }
        __builtin_amdgcn_s_setprio(0);
        // ---- softmax: in-lane reductions (row i = lane&15) ----
        float lm = -1e30f;
        #pragma unroll
        for (int tt = 0; tt < 4; tt++)
            #pragma unroll
            for (int r = 0; r < 4; r++) lm = fmaxf(lm, s[tt][r]);
        lm = fmaxf(lm, __shfl_xor(lm, 16));
        lm = fmaxf(lm, __shfl_xor(lm, 32));   // full tile-max for this row
        float tmax = lm - m;
        tmax = fmaxf(tmax, __shfl_xor(tmax, 1));
        tmax = fmaxf(tmax, __shfl_xor(tmax, 2));
        tmax = fmaxf(tmax, __shfl_xor(tmax, 4));
        tmax = fmaxf(tmax, __shfl_xor(tmax, 8));
        if (tmax > THRRAW) {    // wave-uniform rescale (rare after first tile)
            float mn = fmaxf(m, lm);
            float corr = exp2f((m - mn) * SCL);
            m = mn;
            l *= corr;
            #pragma unroll
            for (int r = 0; r < 4; r++) {
                float cr_ = __shfl(corr, (lane & 48) | ((lane >> 4) * 4 + r));
                #pragma unroll
                for (int ct = 0; ct < 16; ct++) o[ct][r] *= cr_;
            }
        }
        // P = exp2((S-m)*SCL): 4 j-consecutive values per (tt) -> one b64 write each
        float rs = 0.f;
        #pragma unroll
        for (int tt = 0; tt < 4; tt++) {
            unsigned long long pw = 0ull;
            #pragma unroll
            for (int r = 0; r < 4; r++) {
                float p = exp2f((s[tt][r] - m) * SCL);
                rs += p;
                pw |= (unsigned long long)f2b(p) << (r * 16);
            }
            unsigned off = ((unsigned)((lane & 15) * 128 + tt * 32 + ((lane >> 4) * 8)))
                           ^ (((unsigned)(lane & 7)) << 4);
            *(unsigned long long*)((char*)&Ps[w][0] + off) = pw;
        }
        rs += __shfl_xor(rs, 16);
        rs += __shfl_xor(rs, 32);
        l += rs;
        // O += P V (wave-local P; no barrier needed)
        __builtin_amdgcn_s_setprio(1);
        #pragma unroll
        for (int kk = 0; kk < 2; kk++) {
            unsigned offp = ((unsigned)((lane & 15) * 128 + kk * 64 + ((lane >> 4) * 16)))
                            ^ (((unsigned)(lane & 7)) << 4);
            bf16x8 pf = *(const bf16x8*)((char*)&Ps[w][0] + offp);
            #pragma unroll
            for (int ct = 0; ct < 16; ct++) {
                unsigned offv = ((unsigned)((ct * 16 + (lane & 15)) * 128 + kk * 64 + ((lane >> 4) * 16)))
                                ^ (((unsigned)(lane & 7)) << 4);
                bf16x8 vf = *(const bf16x8*)(VsB + offv);
                o[ct] = __builtin_amdgcn_mfma_f32_16x16x32_bf16(pf, vf, o[ct], 0, 0, 0);
            }
        }
        __builtin_amdgcn_s_setprio(0);
        __syncthreads();   // drains glds (vmcnt) + protects buffer reuse
        cur ^= 1;
    }
    // write unnormalized partial O and (m, l)
    unsigned short* dst = po + (size_t)(sp * NB + b) * NN * NC;
    #pragma unroll
    for (int ct = 0; ct < 16; ct++) {
        #pragma unroll
        for (int r = 0; r < 4; r++) {
            int i = i0 + w * 16 + (lane >> 4) * 4 + r;
            dst[(size_t)i * NC + ct * 16 + (lane & 15)] = f2b(o[ct][r]);
        }
    }
    if (lane < 16) {
        int i = i0 + w * 16 + lane;
        size_t mi = ((size_t)(sp * NB + b) * NN + i) * 2;
        ml[mi] = m;
        ml[mi + 1] = l;
    }
}

// ---------------- fused combine + projection + residual ----------------
// block: i-tile 32, all 256 o. C[o][i] = sum_c wp[o][c] ho[i][c]; out = x + C + bp.
__global__ __launch_bounds__(256, 4) void k_proj(
        const unsigned short* __restrict__ po, const float* __restrict__ ml,
        const unsigned short* __restrict__ wp_b, const float* __restrict__ bp,
        const float* __restrict__ x, float* __restrict__ out) {
    __shared__ __attribute__((aligned(16))) unsigned short Hs[32 * 256]; // [i 32][c 256] swz
    int i0 = blockIdx.x * 32, b = blockIdx.y;
    int tid = threadIdx.x, lane = tid & 63, w = tid >> 6;
    {   // combine SPLIT splits -> Hs (combine weights computed inline)
        int il = tid >> 3, cq = tid & 7;
        int i = i0 + il;
        float mv[SPLIT], lv[SPLIT];
        float M = -1e30f;
        #pragma unroll
        for (int s = 0; s < SPLIT; s++) {
            size_t mi = ((size_t)(s * NB + b) * NN + i) * 2;
            mv[s] = ml[mi]; lv[s] = ml[mi + 1];
            M = fmaxf(M, mv[s]);
        }
        float den = 0.f, wg[SPLIT];
        #pragma unroll
        for (int s = 0; s < SPLIT; s++) { wg[s] = exp2f((mv[s] - M) * SCL); den += wg[s] * lv[s]; }
        float inv = 1.f / den;
        #pragma unroll
        for (int s = 0; s < SPLIT; s++) wg[s] *= inv;
        #pragma unroll
        for (int e = 0; e < 4; e++) {
            float accv[8];
            #pragma unroll
            for (int q = 0; q < 8; q++) accv[q] = 0.f;
            #pragma unroll
            for (int s = 0; s < SPLIT; s++) {
                u16x8 v = *(const u16x8*)(po + ((size_t)(s * NB + b) * NN + i) * NC + cq * 32 + e * 8);
                #pragma unroll
                for (int q = 0; q < 8; q++) accv[q] += wg[s] * b2f(v[q]);
            }
            u16x8 rv;
            #pragma unroll
            for (int q = 0; q < 8; q++) rv[q] = f2b(accv[q]);
            unsigned off = ((unsigned)(il * 512 + cq * 64 + e * 16)) ^ ((il & 7) << 4);
            *(u16x8*)((char*)Hs + off) = rv;
        }
    }
    __syncthreads();
    // GEMM: wave w owns o-range [w*64, +64); acc[4 mt][2 nt]
    f32x4 acc[4][2];
    #pragma unroll
    for (int mt = 0; mt < 4; mt++)
        #pragma unroll
        for (int nt = 0; nt < 2; nt++) acc[mt][nt] = (f32x4){0.f, 0.f, 0.f, 0.f};
    #pragma unroll
    for (int kk = 0; kk < 8; kk++) {
        bf16x8 bfr[2];
        #pragma unroll
        for (int nt = 0; nt < 2; nt++) {
            unsigned off = ((unsigned)((nt * 16 + (lane & 15)) * 512 + kk * 64 + ((lane >> 4) * 16)))
                           ^ (((unsigned)(lane & 7)) << 4);
            bfr[nt] = *(const bf16x8*)((char*)Hs + off);
        }
        #pragma unroll
        for (int mt = 0; mt < 4; mt++) {
            bf16x8 af = *(const bf16x8*)(wp_b + (size_t)(w * 64 + mt * 16 + (lane & 15)) * NC
                                         + kk * 32 + ((lane >> 4) * 8));
            #pragma unroll
            for (int nt = 0; nt < 2; nt++)
                acc[mt][nt] = __builtin_amdgcn_mfma_f32_16x16x32_bf16(af, bfr[nt], acc[mt][nt], 0, 0, 0);
        }
    }
    #pragma unroll
    for (int mt = 0; mt < 4; mt++) {
        #pragma unroll
        for (int r = 0; r < 4; r++) {
            int o = w * 64 + mt * 16 + (lane >> 4) * 4 + r;
            float bv_ = bp[o];
            #pragma unroll
            for (int nt = 0; nt < 2; nt++) {
                int i = i0 + nt * 16 + (lane & 15);
                size_t idx = ((size_t)b * NC + o) * NN + i;
                out[idx] = x[idx] + acc[mt][nt][r] + bv_;
            }
        }
    }
}

extern "C" void kernel_launch(void* const* d_in, const int* in_sizes, int n_in,
                              void* d_out, int out_size, void* d_ws, size_t ws_size,
                              hipStream_t stream) {
    const float* x     = (const float*)d_in[0];
    const float* gamma = (const float*)d_in[1];
    const float* beta  = (const float*)d_in[2];
    const float* wq    = (const float*)d_in[3];
    const float* bq    = (const float*)d_in[4];
    const float* wk    = (const float*)d_in[5];
    const float* bk    = (const float*)d_in[6];
    const float* wv    = (const float*)d_in[7];
    const float* bv    = (const float*)d_in[8];
    const float* wp    = (const float*)d_in[9];
    const float* bp    = (const float*)d_in[10];
    float* out = (float*)d_out;

    char* ws = (char*)d_ws;
    const size_t MB = 1024 * 1024;
    float*          stats = (float*)ws;                        // 1 KB (zeroed)
    unsigned short* wb    = (unsigned short*)(ws + 1024);      // 512 KB
    unsigned short* q_t   = (unsigned short*)(ws + 1 * MB);    // 4 MB
    unsigned short* k_t   = (unsigned short*)(ws + 5 * MB);    // 4 MB
    unsigned short* v_cm  = (unsigned short*)(ws + 9 * MB);    // 4 MB
    float*          ml    = (float*)(ws + 13 * MB);            // 512 KB
    unsigned short* hn_t  = (unsigned short*)(ws + 14 * MB);   // 4 MB (dead after k_qkv)
    unsigned short* po    = (unsigned short*)(ws + 14 * MB);   // 16 MB, aliases hn_t

    hipMemsetAsync(stats, 0, 1024, stream);
    k_wcvt<<<256, 256, 0, stream>>>(wq, wk, wv, wp, wb);
    k_stats<<<256, 256, 0, stream>>>(x, stats);
    k_norm_t<<<dim3(NN / 64, NC / 64, NB), 256, 0, stream>>>(x, gamma, beta, stats, hn_t);
    k_qkv<<<dim3(NN / 64, 3, NB), 256, 0, stream>>>(hn_t, wb, bq, bk, bv, q_t, k_t, v_cm);
    k_attn<<<256, 512, 0, stream>>>(q_t, k_t, v_cm, po, ml);
    k_proj<<<dim3(NN / 32, NB), 256, 0, stream>>>(po, ml, wb + 3 * 65536, bp, x, out);
}

// Round 10
// 186.530 us; speedup vs baseline: 2.7982x; 1.0897x over previous
//
#include <hip/hip_runtime.h>
#include <hip/hip_bf16.h>

#define NB 2
#define NC 256
#define NN 4096
#define NG 16
#define GSZ (16*NN)      // elements per (b,group) = 65536, contiguous in x
#define SPLIT 4
#define JT (NN / SPLIT / 64)   // j-tiles per split = 16
#define SCL 0.09014205f  // log2(e) / sqrt(256)
#define THRRAW 88.0f     // defer-max threshold in raw score units (~8/SCL)

typedef __attribute__((ext_vector_type(8))) short bf16x8;
typedef __attribute__((ext_vector_type(4))) float f32x4;
typedef __attribute__((ext_vector_type(8))) unsigned short u16x8;

static __device__ __forceinline__ unsigned short f2b(float f) {
    union { float f; unsigned u; } x; x.f = f;
    unsigned r = x.u + 0x7fffu + ((x.u >> 16) & 1u);
    return (unsigned short)(r >> 16);
}
static __device__ __forceinline__ float b2f(unsigned short u) {
    union { unsigned u; float f; } x; x.u = ((unsigned)u) << 16;
    return x.f;
}
// async global->LDS, 16B per lane; LDS dest must be wave-uniform base (+lane*16)
static __device__ __forceinline__ void glds16(const void* g, void* l) {
    __builtin_amdgcn_global_load_lds(
        (const __attribute__((address_space(1))) unsigned int*)g,
        (__attribute__((address_space(3))) unsigned int*)l, 16, 0, 0);
}

// ---------------- fused: group-norm sums (blocks 0..255) + weight cvt (256..511) ----
__global__ void k_pre(const float* __restrict__ wq, const float* __restrict__ wk,
                      const float* __restrict__ wv, const float* __restrict__ wp,
                      unsigned short* __restrict__ wbd,
                      const float* __restrict__ x, float* __restrict__ stats) {
    __shared__ float r1[4], r2[4];
    int bx = blockIdx.x;
    if (bx < 256) {
        int bg = bx >> 3, seg = bx & 7;   // 32 groups x 8 segments
        const float4* p = (const float4*)(x + (size_t)bg * GSZ + (size_t)seg * (GSZ / 8));
        float s1 = 0.f, s2 = 0.f;
        for (int k = threadIdx.x; k < GSZ / 8 / 4; k += 256) {
            float4 v = p[k];
            s1 += v.x + v.y + v.z + v.w;
            s2 += v.x*v.x + v.y*v.y + v.z*v.z + v.w*v.w;
        }
        #pragma unroll
        for (int m = 1; m < 64; m <<= 1) { s1 += __shfl_xor(s1, m); s2 += __shfl_xor(s2, m); }
        int w = threadIdx.x >> 6;
        if ((threadIdx.x & 63) == 0) { r1[w] = s1; r2[w] = s2; }
        __syncthreads();
        if (threadIdx.x == 0) {
            float a = 0.f, b = 0.f;
            #pragma unroll
            for (int i = 0; i < 4; i++) { a += r1[i]; b += r2[i]; }
            atomicAdd(&stats[bg * 2], a);
            atomicAdd(&stats[bg * 2 + 1], b);
        }
    } else {
        int idx = ((bx - 256) * 256 + threadIdx.x) * 4;   // 0..262140
        int which = idx >> 16, off = idx & 65535;
        const float* s = (which == 0) ? wq : (which == 1) ? wk : (which == 2) ? wv : wp;
        float4 v = *(const float4*)(s + off);
        wbd[idx + 0] = f2b(v.x);
        wbd[idx + 1] = f2b(v.y);
        wbd[idx + 2] = f2b(v.z);
        wbd[idx + 3] = f2b(v.w);
    }
}

// ---------------- fused norm + QKV GEMM ----------------
// block (i0=32 rows, b): normalize x -> LDS hs[32 i][256 c] (swizzled), then
// Q,K: C[i][o] (wave-split o) -> q_t/k_t[b][n][c]; V: C[o][i] -> v_cm[b][c][n].
__global__ __launch_bounds__(256, 2) void k_qkvn(
        const float* __restrict__ x, const float* __restrict__ gamma,
        const float* __restrict__ beta, const float* __restrict__ stats,
        const unsigned short* __restrict__ wb,
        const float* __restrict__ bq, const float* __restrict__ bk, const float* __restrict__ bv,
        unsigned short* __restrict__ q_t, unsigned short* __restrict__ k_t,
        unsigned short* __restrict__ v_cm) {
    __shared__ __attribute__((aligned(16))) unsigned short hs[32 * 256]; // [i][c] swz
    int i0 = blockIdx.x * 32, b = blockIdx.y;
    int tid = threadIdx.x, lane = tid & 63, w = tid >> 6;
    {   // phase 0: thread = one channel c; read 32 n coalesced, normalize, scatter to LDS
        int c = tid;
        float s1 = stats[(b * NG + (c >> 4)) * 2];
        float s2 = stats[(b * NG + (c >> 4)) * 2 + 1];
        float mean = s1 * (1.f / (float)GSZ);
        float var  = s2 * (1.f / (float)GSZ) - mean * mean;
        float rstd = rsqrtf(var + 1e-6f);
        float sc = rstd * gamma[c];
        float sh = beta[c] - mean * sc;
        const float4* row = (const float4*)(x + ((size_t)b * NC + c) * NN + i0);
        #pragma unroll
        for (int q = 0; q < 8; q++) {
            float4 v = row[q];
            float vals[4] = {v.x, v.y, v.z, v.w};
            #pragma unroll
            for (int e = 0; e < 4; e++) {
                int i = q * 4 + e;
                unsigned off = (unsigned)(i * 512 + ((c * 2) ^ ((i & 7) << 4)));
                *(unsigned short*)((char*)hs + off) = f2b(vals[e] * sc + sh);
            }
        }
    }
    __syncthreads();
    // Q and K phases: C[i 32][o 256], wave w owns o-range [w*64, +64)
    #pragma unroll 1
    for (int which = 0; which < 2; ++which) {
        const unsigned short* W = wb + which * 65536;
        const float* bias = (which == 0) ? bq : bk;
        unsigned short* dst = ((which == 0) ? q_t : k_t) + (size_t)b * NN * NC;
        f32x4 acc[2][4];
        #pragma unroll
        for (int it = 0; it < 2; it++)
            #pragma unroll
            for (int ot = 0; ot < 4; ot++) acc[it][ot] = (f32x4){0.f, 0.f, 0.f, 0.f};
        #pragma unroll
        for (int kk = 0; kk < 8; kk++) {
            bf16x8 af[2];
            #pragma unroll
            for (int it = 0; it < 2; it++) {
                unsigned row = (unsigned)(it * 16 + (lane & 15));
                unsigned off = row * 512 + (((unsigned)(kk * 64 + ((lane >> 4) * 16))) ^ ((row & 7) << 4));
                af[it] = *(const bf16x8*)((char*)hs + off);
            }
            #pragma unroll
            for (int ot = 0; ot < 4; ot++) {
                bf16x8 bf_ = *(const bf16x8*)(W + (size_t)(w * 64 + ot * 16 + (lane & 15)) * NC
                                              + kk * 32 + ((lane >> 4) * 8));
                #pragma unroll
                for (int it = 0; it < 2; it++)
                    acc[it][ot] = __builtin_amdgcn_mfma_f32_16x16x32_bf16(af[it], bf_, acc[it][ot], 0, 0, 0);
            }
        }
        #pragma unroll
        for (int it = 0; it < 2; it++) {
            #pragma unroll
            for (int ot = 0; ot < 4; ot++) {
                int o = w * 64 + ot * 16 + (lane & 15);
                float bv_ = bias[o];
                #pragma unroll
                for (int r = 0; r < 4; r++) {
                    int i = i0 + it * 16 + (lane >> 4) * 4 + r;
                    dst[(size_t)i * NC + o] = f2b(acc[it][ot][r] + bv_);
                }
            }
        }
    }
    // V phase: C[o 256][i 32], wave w owns o-range [w*64, +64)
    {
        const unsigned short* W = wb + 2 * 65536;
        f32x4 acc[4][2];
        #pragma unroll
        for (int mt = 0; mt < 4; mt++)
            #pragma unroll
            for (int nt = 0; nt < 2; nt++) acc[mt][nt] = (f32x4){0.f, 0.f, 0.f, 0.f};
        #pragma unroll
        for (int kk = 0; kk < 8; kk++) {
            bf16x8 bfr[2];
            #pragma unroll
            for (int nt = 0; nt < 2; nt++) {
                unsigned row = (unsigned)(nt * 16 + (lane & 15));
                unsigned off = row * 512 + (((unsigned)(kk * 64 + ((lane >> 4) * 16))) ^ ((row & 7) << 4));
                bfr[nt] = *(const bf16x8*)((char*)hs + off);
            }
            #pragma unroll
            for (int mt = 0; mt < 4; mt++) {
                bf16x8 af = *(const bf16x8*)(W + (size_t)(w * 64 + mt * 16 + (lane & 15)) * NC
                                             + kk * 32 + ((lane >> 4) * 8));
                #pragma unroll
                for (int nt = 0; nt < 2; nt++)
                    acc[mt][nt] = __builtin_amdgcn_mfma_f32_16x16x32_bf16(af, bfr[nt], acc[mt][nt], 0, 0, 0);
            }
        }
        #pragma unroll
        for (int mt = 0; mt < 4; mt++) {
            #pragma unroll
            for (int r = 0; r < 4; r++) {
                int o = w * 64 + mt * 16 + (lane >> 4) * 4 + r;
                float bv_ = bv[o];
                #pragma unroll
                for (int nt = 0; nt < 2; nt++) {
                    int i = i0 + nt * 16 + (lane & 15);
                    v_cm[(size_t)b * NC * NN + (size_t)o * NN + i] = f2b(acc[mt][nt][r] + bv_);
                }
            }
        }
    }
}

// ---------------- flash attention: 8 waves x 16 i-rows, K+V dbuf glds, defer-max ----
// SWAPPED QK^T: S computed as mfma(K,Q) so lane holds S[i=lane&15][j-subset] ->
// in-lane softmax reductions (VALU, not LDS shuffles) + b64-packed P writes.
// grid 256: bid&7 -> (sp,b) (XCD-grouped), bid>>3 -> i-block (128 rows).
// NOTE: never bound above 2 waves/SIMD here — o[16]+qf[8] needs ~190 unified regs (r5/r7).
__global__ __launch_bounds__(512, 2) void k_attn(
        const unsigned short* __restrict__ q_t, const unsigned short* __restrict__ k_t,
        const unsigned short* __restrict__ v_cm,
        unsigned short* __restrict__ po, float* __restrict__ ml) {
    __shared__ __attribute__((aligned(16))) unsigned short Ks[2][16384]; // [j 64][c 256] swz
    __shared__ __attribute__((aligned(16))) unsigned short Vs[2][16384]; // [c 256][j 64] swz
    __shared__ __attribute__((aligned(16))) unsigned short Ps[8][1024];  // [i 16][j 64] swz
    int bid = blockIdx.x;
    int g = bid & 7, xb = bid >> 3;
    int sp = g & 3, b = g >> 2;
    int i0 = xb * 128;
    int lane = threadIdx.x & 63, w = threadIdx.x >> 6;
    size_t bO = (size_t)b * NN * NC;
    // Q fragments (wave w owns rows i0+w*16 .. +16); used as MFMA B-operand
    bf16x8 qf[8];
    {
        const unsigned short* qrow =
            q_t + bO + (size_t)(i0 + w * 16 + (lane & 15)) * NC + ((lane >> 4) * 8);
        #pragma unroll
        for (int kk = 0; kk < 8; kk++) qf[kk] = *(const bf16x8*)(qrow + kk * 32);
    }
    // per-lane pre-swizzled global source offsets (linear LDS dest -> inverse-swz source)
    unsigned kstat[4], vstat[4];
    #pragma unroll
    for (int r = 0; r < 4; r++) {
        int jr = r * 16 + w * 2 + (lane >> 5);
        kstat[r] = (unsigned)(jr * 512 + (((lane & 31) * 16) ^ ((jr & 7) << 4)));
        int cr = r * 64 + w * 8 + (lane >> 3);
        vstat[r] = (unsigned)(cr * 8192 + (((lane & 7) * 16) ^ ((cr & 7) << 4)));
    }
    const char* kp = (const char*)(k_t + bO) + (size_t)sp * 524288;  // sp*1024 rows * 512B
    const char* vp = (const char*)(v_cm + bO) + (size_t)sp * 2048;   // sp*1024 j * 2B
    f32x4 o[16];
    #pragma unroll
    for (int t = 0; t < 16; t++) o[t] = (f32x4){0.f, 0.f, 0.f, 0.f};
    float m = -1e30f, l = 0.f;   // per-lane: row i = lane&15
    // prologue: stage tile 0 into buf 0
    #pragma unroll
    for (int r = 0; r < 4; r++) {
        glds16(kp + kstat[r], (char*)&Ks[0][0] + w * 1024 + r * 8192);
        glds16(vp + vstat[r], (char*)&Vs[0][0] + w * 1024 + r * 8192);
    }
    __syncthreads();
    int cur = 0;
    #pragma unroll 1
    for (int t = 0; t < JT; ++t) {
        if (t < JT - 1) {   // issue next-tile staging into alt buffer (overlaps compute)
            kp += 32768; vp += 128;
            int nb = cur ^ 1;
            #pragma unroll
            for (int r = 0; r < 4; r++) {
                glds16(kp + kstat[r], (char*)&Ks[nb][0] + w * 1024 + r * 8192);
                glds16(vp + vstat[r], (char*)&Vs[nb][0] + w * 1024 + r * 8192);
            }
        }
        const char* KsB = (const char*)&Ks[cur][0];
        const char* VsB = (const char*)&Vs[cur][0];
        // S^T tiles: mfma(A=K j-rows, B=Q i-cols) -> lane holds
        // S[i=lane&15][j = tt*16 + (lane>>4)*4 + r]
        f32x4 s[4];
        #pragma unroll
        for (int tt = 0; tt < 4; tt++) s[tt] = (f32x4){0.f, 0.f, 0.f, 0.f};
        __builtin_amdgcn_s_setprio(1);
        #pragma unroll
        for (int kk = 0; kk < 8; kk++) {
            #pragma unroll
            for (int tt = 0; tt < 4; tt++) {
                unsigned off = ((unsigned)((tt * 16 + (lane & 15)) * 512 + kk * 64 + ((lane >> 4) * 16)))
                               ^ (((unsigned)(lane & 7)) << 4);
                bf16x8 kf = *(const bf16x8*)(KsB + off);
                s[tt] = __builtin_amdgcn_mfma_f32_16x16x32_bf16(kf, qf[kk], s[tt], 0, 0, 0);
            }
        }
        __builtin_amdgcn_s_setprio(0);
        // ---- softmax: in-lane reductions (row i = lane&15) ----
        float lm = -1e30f;
        #pragma unroll
        for (int tt = 0; tt < 4; tt++)
            #pragma unroll
            for (int r = 0; r < 4; r++) lm = fmaxf(lm, s[tt][r]);
        lm = fmaxf(lm, __shfl_xor(lm, 16));
        lm = fmaxf(lm, __shfl_xor(lm, 32));   // full tile-max for this row
        float tmax = lm - m;
        tmax = fmaxf(tmax, __shfl_xor(tmax, 1));
        tmax = fmaxf(tmax, __shfl_xor(tmax, 2));
        tmax = fmaxf(tmax, __shfl_xor(tmax, 4));
        tmax = fmaxf(tmax, __shfl_xor(tmax, 8));
        if (tmax > THRRAW) {    // wave-uniform rescale (rare after first tile)
            float mn = fmaxf(m, lm);
            float corr = exp2f((m - mn) * SCL);
            m = mn;
            l *= corr;
            #pragma unroll
            for (int r = 0; r < 4; r++) {
                float cr_ = __shfl(corr, (lane & 48) | ((lane >> 4) * 4 + r));
                #pragma unroll
                for (int ct = 0; ct < 16; ct++) o[ct][r] *= cr_;
            }
        }
        // P = exp2((S-m)*SCL): 4 j-consecutive values per (tt) -> one b64 write each
        float rs = 0.f;
        #pragma unroll
        for (int tt = 0; tt < 4; tt++) {
            unsigned long long pw = 0ull;
            #pragma unroll
            for (int r = 0; r < 4; r++) {
                float p = exp2f((s[tt][r] - m) * SCL);
                rs += p;
                pw |= (unsigned long long)f2b(p) << (r * 16);
            }
            unsigned off = ((unsigned)((lane & 15) * 128 + tt * 32 + ((lane >> 4) * 8)))
                           ^ (((unsigned)(lane & 7)) << 4);
            *(unsigned long long*)((char*)&Ps[w][0] + off) = pw;
        }
        rs += __shfl_xor(rs, 16);
        rs += __shfl_xor(rs, 32);
        l += rs;
        // O += P V (wave-local P; no barrier needed)
        __builtin_amdgcn_s_setprio(1);
        #pragma unroll
        for (int kk = 0; kk < 2; kk++) {
            unsigned offp = ((unsigned)((lane & 15) * 128 + kk * 64 + ((lane >> 4) * 16)))
                            ^ (((unsigned)(lane & 7)) << 4);
            bf16x8 pf = *(const bf16x8*)((char*)&Ps[w][0] + offp);
            #pragma unroll
            for (int ct = 0; ct < 16; ct++) {
                unsigned offv = ((unsigned)((ct * 16 + (lane & 15)) * 128 + kk * 64 + ((lane >> 4) * 16)))
                                ^ (((unsigned)(lane & 7)) << 4);
                bf16x8 vf = *(const bf16x8*)(VsB + offv);
                o[ct] = __builtin_amdgcn_mfma_f32_16x16x32_bf16(pf, vf, o[ct], 0, 0, 0);
            }
        }
        __builtin_amdgcn_s_setprio(0);
        __syncthreads();   // drains glds (vmcnt) + protects buffer reuse
        cur ^= 1;
    }
    // write unnormalized partial O and (m, l)
    unsigned short* dst = po + (size_t)(sp * NB + b) * NN * NC;
    #pragma unroll
    for (int ct = 0; ct < 16; ct++) {
        #pragma unroll
        for (int r = 0; r < 4; r++) {
            int i = i0 + w * 16 + (lane >> 4) * 4 + r;
            dst[(size_t)i * NC + ct * 16 + (lane & 15)] = f2b(o[ct][r]);
        }
    }
    if (lane < 16) {
        int i = i0 + w * 16 + lane;
        size_t mi = ((size_t)(sp * NB + b) * NN + i) * 2;
        ml[mi] = m;
        ml[mi + 1] = l;
    }
}

// ---------------- fused combine + projection + residual ----------------
// block: i-tile 32, all 256 o. C[o][i] = sum_c wp[o][c] ho[i][c]; out = x + C + bp.
__global__ __launch_bounds__(256, 4) void k_proj(
        const unsigned short* __restrict__ po, const float* __restrict__ ml,
        const unsigned short* __restrict__ wp_b, const float* __restrict__ bp,
        const float* __restrict__ x, float* __restrict__ out) {
    __shared__ __attribute__((aligned(16))) unsigned short Hs[32 * 256]; // [i 32][c 256] swz
    int i0 = blockIdx.x * 32, b = blockIdx.y;
    int tid = threadIdx.x, lane = tid & 63, w = tid >> 6;
    {   // combine SPLIT splits -> Hs (combine weights computed inline)
        int il = tid >> 3, cq = tid & 7;
        int i = i0 + il;
        float mv[SPLIT], lv[SPLIT];
        float M = -1e30f;
        #pragma unroll
        for (int s = 0; s < SPLIT; s++) {
            size_t mi = ((size_t)(s * NB + b) * NN + i) * 2;
            mv[s] = ml[mi]; lv[s] = ml[mi + 1];
            M = fmaxf(M, mv[s]);
        }
        float den = 0.f, wg[SPLIT];
        #pragma unroll
        for (int s = 0; s < SPLIT; s++) { wg[s] = exp2f((mv[s] - M) * SCL); den += wg[s] * lv[s]; }
        float inv = 1.f / den;
        #pragma unroll
        for (int s = 0; s < SPLIT; s++) wg[s] *= inv;
        #pragma unroll
        for (int e = 0; e < 4; e++) {
            float accv[8];
            #pragma unroll
            for (int q = 0; q < 8; q++) accv[q] = 0.f;
            #pragma unroll
            for (int s = 0; s < SPLIT; s++) {
                u16x8 v = *(const u16x8*)(po + ((size_t)(s * NB + b) * NN + i) * NC + cq * 32 + e * 8);
                #pragma unroll
                for (int q = 0; q < 8; q++) accv[q] += wg[s] * b2f(v[q]);
            }
            u16x8 rv;
            #pragma unroll
            for (int q = 0; q < 8; q++) rv[q] = f2b(accv[q]);
            unsigned off = ((unsigned)(il * 512 + cq * 64 + e * 16)) ^ ((il & 7) << 4);
            *(u16x8*)((char*)Hs + off) = rv;
        }
    }
    __syncthreads();
    // GEMM: wave w owns o-range [w*64, +64); acc[4 mt][2 nt]
    f32x4 acc[4][2];
    #pragma unroll
    for (int mt = 0; mt < 4; mt++)
        #pragma unroll
        for (int nt = 0; nt < 2; nt++) acc[mt][nt] = (f32x4){0.f, 0.f, 0.f, 0.f};
    #pragma unroll
    for (int kk = 0; kk < 8; kk++) {
        bf16x8 bfr[2];
        #pragma unroll
        for (int nt = 0; nt < 2; nt++) {
            unsigned off = ((unsigned)((nt * 16 + (lane & 15)) * 512 + kk * 64 + ((lane >> 4) * 16)))
                           ^ (((unsigned)(lane & 7)) << 4);
            bfr[nt] = *(const bf16x8*)((char*)Hs + off);
        }
        #pragma unroll
        for (int mt = 0; mt < 4; mt++) {
            bf16x8 af = *(const bf16x8*)(wp_b + (size_t)(w * 64 + mt * 16 + (lane & 15)) * NC
                                         + kk * 32 + ((lane >> 4) * 8));
            #pragma unroll
            for (int nt = 0; nt < 2; nt++)
                acc[mt][nt] = __builtin_amdgcn_mfma_f32_16x16x32_bf16(af, bfr[nt], acc[mt][nt], 0, 0, 0);
        }
    }
    #pragma unroll
    for (int mt = 0; mt < 4; mt++) {
        #pragma unroll
        for (int r = 0; r < 4; r++) {
            int o = w * 64 + mt * 16 + (lane >> 4) * 4 + r;
            float bv_ = bp[o];
            #pragma unroll
            for (int nt = 0; nt < 2; nt++) {
                int i = i0 + nt * 16 + (lane & 15);
                size_t idx = ((size_t)b * NC + o) * NN + i;
                out[idx] = x[idx] + acc[mt][nt][r] + bv_;
            }
        }
    }
}

extern "C" void kernel_launch(void* const* d_in, const int* in_sizes, int n_in,
                              void* d_out, int out_size, void* d_ws, size_t ws_size,
                              hipStream_t stream) {
    const float* x     = (const float*)d_in[0];
    const float* gamma = (const float*)d_in[1];
    const float* beta  = (const float*)d_in[2];
    const float* wq    = (const float*)d_in[3];
    const float* bq    = (const float*)d_in[4];
    const float* wk    = (const float*)d_in[5];
    const float* bk    = (const float*)d_in[6];
    const float* wv    = (const float*)d_in[7];
    const float* bv    = (const float*)d_in[8];
    const float* wp    = (const float*)d_in[9];
    const float* bp    = (const float*)d_in[10];
    float* out = (float*)d_out;

    char* ws = (char*)d_ws;
    const size_t MB = 1024 * 1024;
    float*          stats = (float*)ws;                        // 1 KB (zeroed)
    unsigned short* wb    = (unsigned short*)(ws + 1024);      // 512 KB
    unsigned short* q_t   = (unsigned short*)(ws + 1 * MB);    // 4 MB
    unsigned short* k_t   = (unsigned short*)(ws + 5 * MB);    // 4 MB
    unsigned short* v_cm  = (unsigned short*)(ws + 9 * MB);    // 4 MB
    float*          ml    = (float*)(ws + 13 * MB);            // 512 KB
    unsigned short* po    = (unsigned short*)(ws + 14 * MB);   // 16 MB

    hipMemsetAsync(stats, 0, 1024, stream);
    k_pre<<<512, 256, 0, stream>>>(wq, wk, wv, wp, wb, x, stats);
    k_qkvn<<<dim3(NN / 32, NB), 256, 0, stream>>>(x, gamma, beta, stats, wb,
                                                  bq, bk, bv, q_t, k_t, v_cm);
    k_attn<<<256, 512, 0, stream>>>(q_t, k_t, v_cm, po, ml);
    k_proj<<<dim3(NN / 32, NB), 256, 0, stream>>>(po, ml, wb + 3 * 65536, bp, x, out);
}